// Round 6
// baseline (356.986 us; speedup 1.0000x reference)
//
#include <hip/hip_runtime.h>
#include <hip/hip_cooperative_groups.h>

namespace cg = cooperative_groups;

// FeatureAlign, MI355X. N=4, D=256, H=W=64, fp32.
// Single cooperative kernel, 3 phases:
//   P1: 12-offset dot products (row-load + 9 clamped __shfl), partials -> ws
//   P2: split-reduce + pn^2 gather + weight math -> ws
//   P3: streaming apply (mem + 4 weighted gathers -> out)
// Unit mapping u = 4*(r+64n)+s keeps all d-splits of one (r,n) AND its
// phase-2 reducer on the same XCD -> partials stay in XCD-local L2.

#define HH 64
#define WW 64
#define DD 256
#define HWD (HH * WW)
#define SPLITS 4
#define CPB (DD / SPLITS)   // 64 channels per split-unit
#define CPT (CPB / 8)       // 8 channels per thread

#define NACC 14             // 0..11 dots, 12 pn^2(own), 13 cn^2(own)

// d_ws float layout:
//   P[s][n][r][a][x] : 4*4*64*14*64 = 917,504 floats (3.67 MB)
//   W[n][j][r][x]    : 4*5*64*64    =  81,920 floats (0.33 MB)
#define P_IDX(s, n, r, a, x) (((((size_t)(s) * 4 + (n)) * HH + (r)) * NACC + (a)) * WW + (x))
#define W_OFF ((size_t)SPLITS * 4 * HH * NACC * WW)
#define W_IDX(n, j, r, x) (W_OFF + ((((size_t)(n) * 5 + (j)) * HH + (r)) * WW + (x)))

__device__ __constant__ int c_ody[12] = {-1,-1,-1, 0,0,0, 1,1,1, -1, 2, 2};
__device__ __constant__ int c_odx[12] = {-1, 0, 1,-1,0,1,-1,0,1,  2,-1, 2};

__global__ __launch_bounds__(512, 8)
void fa_fused(const float* __restrict__ cur, const float* __restrict__ prev,
              const float* __restrict__ mem, float* __restrict__ ws,
              float* __restrict__ out)
{
    cg::grid_group grid = cg::this_grid();

    const int x  = threadIdx.x;   // 0..63 column == lane
    const int tz = threadIdx.y;   // 0..7  wave id
    const int G  = gridDim.x;

    __shared__ float red[NACC][8][WW];   // 28.7 KB (phase 1)
    __shared__ float tot[NACC][WW];      //  3.5 KB (phase 2)
    __shared__ float png[12][WW];        //  3.0 KB (phase 2)

    // ---------------- Phase 1: dot-product partials ----------------
    for (int u0 = blockIdx.x; u0 < 1024; u0 += G) {
        // XCD swizzle: hardware XCD = b%8; give XCD k contiguous u in
        // [128k, 128k+128). u = 4*(r+64n)+s -> all splits of (r,n) local.
        const int u  = ((u0 & 7) << 7) | (u0 >> 3);
        const int s  = u & 3;
        const int rn = u >> 2;
        const int r  = rn & 63;
        const int n  = rn >> 6;

        const size_t noff = (size_t)n * DD * HWD;
        const float* __restrict__ cur_n  = cur  + noff;
        const float* __restrict__ prev_n = prev + noff;

        const int sm1 = max(x - 1, 0);
        const int sp1 = min(x + 1, WW - 1);
        const int sp2 = min(x + 2, WW - 1);

        const int rA = max(r - 1, 0)      * WW + x;
        const int rB = r                  * WW + x;
        const int rC = min(r + 1, HH - 1) * WW + x;
        const int rD = min(r + 2, HH - 1) * WW + x;

        float acc[NACC];
        #pragma unroll
        for (int a = 0; a < NACC; ++a) acc[a] = 0.f;

        const int d0 = s * CPB + tz * CPT;
        const float* __restrict__ cd = cur_n  + (size_t)d0 * HWD;
        const float* __restrict__ pd = prev_n + (size_t)d0 * HWD;

        float c_ = cd[rB];
        float va = pd[rA];
        float vb = pd[rB];
        float vc = pd[rC];
        float vd = pd[rD];

        #pragma unroll
        for (int k = 0; k < CPT; ++k) {
            float cN = 0.f, aN = 0.f, bN = 0.f, cRN = 0.f, dN = 0.f;
            if (k + 1 < CPT) {
                const float* __restrict__ cd2 = cd + (size_t)(k + 1) * HWD;
                const float* __restrict__ pd2 = pd + (size_t)(k + 1) * HWD;
                cN  = cd2[rB];
                aN  = pd2[rA];
                bN  = pd2[rB];
                cRN = pd2[rC];
                dN  = pd2[rD];
            }

            const float vam = __shfl(va, sm1);
            const float vap = __shfl(va, sp1);
            const float va2 = __shfl(va, sp2);
            const float vbm = __shfl(vb, sm1);
            const float vbp = __shfl(vb, sp1);
            const float vcm = __shfl(vc, sm1);
            const float vcp = __shfl(vc, sp1);
            const float vdm = __shfl(vd, sm1);
            const float vd2 = __shfl(vd, sp2);

            acc[0]  = fmaf(c_, vam, acc[0]);   // (-1,-1)
            acc[1]  = fmaf(c_, va,  acc[1]);   // (-1, 0)
            acc[2]  = fmaf(c_, vap, acc[2]);   // (-1,+1)
            acc[3]  = fmaf(c_, vbm, acc[3]);   // ( 0,-1)
            acc[4]  = fmaf(c_, vb,  acc[4]);   // ( 0, 0)
            acc[5]  = fmaf(c_, vbp, acc[5]);   // ( 0,+1)
            acc[6]  = fmaf(c_, vcm, acc[6]);   // (+1,-1)
            acc[7]  = fmaf(c_, vc,  acc[7]);   // (+1, 0)
            acc[8]  = fmaf(c_, vcp, acc[8]);   // (+1,+1)
            acc[9]  = fmaf(c_, va2, acc[9]);   // (-1,+2)
            acc[10] = fmaf(c_, vdm, acc[10]);  // (+2,-1)
            acc[11] = fmaf(c_, vd2, acc[11]);  // (+2,+2)
            acc[12] = fmaf(vb, vb, acc[12]);   // pn^2 own
            acc[13] = fmaf(c_, c_, acc[13]);   // cn^2 own

            c_ = cN; va = aN; vb = bN; vc = cRN; vd = dN;
        }

        #pragma unroll
        for (int a = 0; a < NACC; ++a) red[a][tz][x] = acc[a];
        __syncthreads();
        for (int a = tz; a < NACC; a += 8) {
            float t = 0.f;
            #pragma unroll
            for (int z = 0; z < 8; ++z) t += red[a][z][x];
            ws[P_IDX(s, n, r, a, x)] = t;
        }
        __syncthreads();
    }

    __threadfence();
    grid.sync();

    // ---------------- Phase 2: weights ----------------
    for (int u0 = blockIdx.x; u0 < 256; u0 += G) {
        // XCD k gets u2 in [32k,32k+32) == same XCD as its partials
        const int u2 = ((u0 & 7) << 5) | (u0 >> 3);
        const int r  = u2 & 63;
        const int n  = u2 >> 6;

        for (int a = tz; a < NACC; a += 8) {
            float t = 0.f;
            #pragma unroll
            for (int s = 0; s < SPLITS; ++s) t += ws[P_IDX(s, n, r, a, x)];
            tot[a][x] = t;
        }
        for (int o = tz; o < 12; o += 8) {
            const int rr = min(max(r + c_ody[o], 0), HH - 1);
            const int xx = min(max(x + c_odx[o], 0), WW - 1);
            float t = 0.f;
            #pragma unroll
            for (int s = 0; s < SPLITS; ++s) t += ws[P_IDX(s, n, rr, 12, xx)];
            png[o][x] = t;
        }
        __syncthreads();

        if (tz == 0) {
            const float cn = sqrtf(tot[13][x]) + 1e-8f;
            float aff[12];
            #pragma unroll
            for (int o = 0; o < 12; ++o) {
                const float pn = sqrtf(png[o][x]) + 1e-8f;
                aff[o] = fmaxf(tot[o][x] / (cn * pn), 0.f);
            }
            float mass = 0.f;
            #pragma unroll
            for (int o = 0; o < 9; ++o) {
                const bool valid = (r + c_ody[o] >= 0) && (r + c_ody[o] < HH) &&
                                   (x + c_odx[o] >= 0) && (x + c_odx[o] < WW);
                if (valid) mass += aff[o];
            }
            const bool  cond      = (mass > -10.f) && (mass < 10.f);
            const float mass_safe = (mass > 0.f) ? mass : 1.f;

            const int aggo[4] = {0, 9, 10, 11};
            #pragma unroll
            for (int j = 0; j < 4; ++j) {
                const int  o     = aggo[j];
                const bool valid = (r + c_ody[o] >= 0) && (r + c_ody[o] < HH) &&
                                   (x + c_odx[o] >= 0) && (x + c_odx[o] < WW);
                const float a = aff[o];
                ws[W_IDX(n, j, r, x)] = (valid && a > 0.f) ? (a / mass_safe) : 0.f;
            }
            ws[W_IDX(n, 4, r, x)] = cond ? 1.f : 0.f;
        }
        __syncthreads();
    }

    __threadfence();
    grid.sync();

    // ---------------- Phase 3: apply ----------------
    for (int u0 = blockIdx.x; u0 < 1024; u0 += G) {
        const int u  = ((u0 & 7) << 7) | (u0 >> 3);
        const int s  = u & 3;
        const int rn = u >> 2;
        const int r  = rn & 63;
        const int n  = rn >> 6;

        const size_t noff = (size_t)n * DD * HWD;
        const float* __restrict__ mem_n = mem + noff;
        float* __restrict__ out_n       = out + noff;

        const float w0 = ws[W_IDX(n, 0, r, x)];
        const float w1 = ws[W_IDX(n, 1, r, x)];
        const float w2 = ws[W_IDX(n, 2, r, x)];
        const float w3 = ws[W_IDX(n, 3, r, x)];
        const float cf = ws[W_IDX(n, 4, r, x)];

        const int ym = max(r - 1, 0), yp = min(r + 2, HH - 1);
        const int xm = max(x - 1, 0), xp = min(x + 2, WW - 1);
        const int p0 = ym * WW + xm;   // (-1,-1)
        const int p1 = ym * WW + xp;   // (-1,+2)
        const int p2 = yp * WW + xm;   // (+2,-1)
        const int p3 = yp * WW + xp;   // (+2,+2)
        const int q  = r * WW + x;

        const int dbase = s * CPB + tz * 8;
        #pragma unroll
        for (int k = 0; k < 8; ++k) {
            const int d = dbase + k;
            const float* __restrict__ md = mem_n + (size_t)d * HWD;
            const float m   = md[q];
            const float agg = w0 * md[p0] + w1 * md[p1] + w2 * md[p2] + w3 * md[p3];
            const float res = m + ((d > 0) ? agg : 0.f);
            out_n[(size_t)d * HWD + q] = (cf != 0.f) ? res : 0.f;
        }
    }
}

extern "C" void kernel_launch(void* const* d_in, const int* in_sizes, int n_in,
                              void* d_out, int out_size, void* d_ws, size_t ws_size,
                              hipStream_t stream)
{
    const float* cur  = (const float*)d_in[0];
    const float* prev = (const float*)d_in[1];
    const float* mem  = (const float*)d_in[2];
    float* out        = (float*)d_out;
    float* ws         = (float*)d_ws;

    // Cooperative grid must be fully co-resident. Query, don't assume.
    int maxPerCU = 0;
    (void)hipOccupancyMaxActiveBlocksPerMultiprocessor(&maxPerCU, fa_fused, 512, 0);
    int G = maxPerCU * 256;          // 256 CUs on MI355X
    if (G > 1024) G = 1024;
    if (G < 8)    G = 8;             // paranoia fallback; grid-stride handles any G

    void* args[] = { (void*)&cur, (void*)&prev, (void*)&mem, (void*)&ws, (void*)&out };
    (void)hipLaunchCooperativeKernel(fa_fused, dim3(G, 1, 1), dim3(64, 8, 1),
                                     args, 0, stream);
}

// Round 7
// 112.797 us; speedup vs baseline: 3.1648x; 3.1648x over previous
//
#include <hip/hip_runtime.h>

// FeatureAlign, MI355X. N=4, D=256, H=W=64, fp32. Two kernels:
//  K1 fa_dots : 12-offset dot partials in "M-space" (shift CUR by 3 shfls
//               per channel instead of shifting PREV by 9), + pn2/cn2.
//  K2 fa_apply: wave0 split-reduces partials, realigns M-space dots with
//               boundary fixes, computes weights; all waves stream mem->out.
// Round-6 lesson: cooperative grid.sync = 476us (10x regression); reverted.

#define HH 64
#define WW 64
#define DD 256
#define HWD (HH * WW)
#define SPLITS 4
#define CPB (DD / SPLITS)   // 64 channels per split-unit
#define CPT (CPB / 8)       // 8 channels per thread

// acc layout (M-space):
//  0 dA0  1 dAm  2 dAp  3 dA2     A = prev row r-1
//  4 dB0  5 dBm  6 dBp            B = prev row r   (own)
//  7 dC0  8 dCm  9 dCp            C = prev row r+1
// 10 dD0 11 dDm 12 dDp 13 dD2     D = prev row r+2
// 14 pn2(own) 15 cn2(own)
// dX0 = sum c[x]*X[x]; dXm = sum c[x+1]*X[x]; dXp = sum c[x-1]*X[x];
// dX2 = sum c[x-2]*X[x].  Final: acc(X,-1)[x]=dXm[x-1] (x=0 -> dX0),
// acc(X,+1)[x]=dXp[x+1] (x=63 -> dX0), acc(X,+2)[x]=dX2[x+2]
// (x=62 -> dXp[63], x=63 -> dX0).
#define NACC 16

// d_ws: P[s][n][r][a][x] : 4*4*64*16*64 = 1,048,576 floats (4 MB)
#define P_IDX(s, n, r, a, x) (((((size_t)(s) * 4 + (n)) * HH + (r)) * NACC + (a)) * WW + (x))

// ---------------- K1: M-space dot partials ----------------
__global__ __launch_bounds__(512)
void fa_dots(const float* __restrict__ cur, const float* __restrict__ prev,
             float* __restrict__ ws)
{
    // XCD-chunk swizzle (1024 = 8 x 128): XCD k gets contiguous r.
    const int b = blockIdx.x;
    const int l = ((b & 7) << 7) | (b >> 3);
    const int r = l & 63;
    const int n = (l >> 6) & 3;
    const int s = l >> 8;

    const int x  = threadIdx.x;   // lane
    const int tz = threadIdx.y;   // 0..7

    const size_t noff = (size_t)n * DD * HWD;
    const float* __restrict__ cur_n  = cur  + noff;
    const float* __restrict__ prev_n = prev + noff;

    const int xp1 = min(x + 1, WW - 1);
    const int xm1 = max(x - 1, 0);
    const int xm2 = max(x - 2, 0);

    const int rA = max(r - 1, 0)      * WW + x;
    const int rB = r                  * WW + x;
    const int rC = min(r + 1, HH - 1) * WW + x;
    const int rD = min(r + 2, HH - 1) * WW + x;

    float acc[NACC];
    #pragma unroll
    for (int a = 0; a < NACC; ++a) acc[a] = 0.f;

    const int d0 = s * CPB + tz * CPT;
    const float* __restrict__ cd = cur_n  + (size_t)d0 * HWD;
    const float* __restrict__ pd = prev_n + (size_t)d0 * HWD;

    float c_ = cd[rB];
    float vA = pd[rA];
    float vB = pd[rB];
    float vC = pd[rC];
    float vD = pd[rD];

    #pragma unroll
    for (int k = 0; k < CPT; ++k) {
        float cN = 0.f, aN = 0.f, bN = 0.f, ccN = 0.f, dN = 0.f;
        if (k + 1 < CPT) {
            const float* __restrict__ cd2 = cd + (size_t)(k + 1) * HWD;
            const float* __restrict__ pd2 = pd + (size_t)(k + 1) * HWD;
            cN  = cd2[rB];
            aN  = pd2[rA];
            bN  = pd2[rB];
            ccN = pd2[rC];
            dN  = pd2[rD];
        }

        // shift CUR: 3 shfls (garbage only in lanes whose M-accs are unused)
        const float cp1 = __shfl(c_, xp1);   // c[x+1]
        const float cm1 = __shfl(c_, xm1);   // c[x-1]
        const float cm2 = __shfl(c_, xm2);   // c[x-2]

        acc[0]  = fmaf(c_,  vA, acc[0]);
        acc[1]  = fmaf(cp1, vA, acc[1]);
        acc[2]  = fmaf(cm1, vA, acc[2]);
        acc[3]  = fmaf(cm2, vA, acc[3]);
        acc[4]  = fmaf(c_,  vB, acc[4]);
        acc[5]  = fmaf(cp1, vB, acc[5]);
        acc[6]  = fmaf(cm1, vB, acc[6]);
        acc[7]  = fmaf(c_,  vC, acc[7]);
        acc[8]  = fmaf(cp1, vC, acc[8]);
        acc[9]  = fmaf(cm1, vC, acc[9]);
        acc[10] = fmaf(c_,  vD, acc[10]);
        acc[11] = fmaf(cp1, vD, acc[11]);
        acc[12] = fmaf(cm1, vD, acc[12]);
        acc[13] = fmaf(cm2, vD, acc[13]);
        acc[14] = fmaf(vB,  vB, acc[14]);   // pn^2 own
        acc[15] = fmaf(c_,  c_, acc[15]);   // cn^2 own

        c_ = cN; vA = aN; vB = bN; vC = ccN; vD = dN;
    }

    __shared__ float red[NACC][8][WW];   // 32 KB
    #pragma unroll
    for (int a = 0; a < NACC; ++a) red[a][tz][x] = acc[a];
    __syncthreads();
    #pragma unroll
    for (int a = tz; a < NACC; a += 8) {
        float t = 0.f;
        #pragma unroll
        for (int z = 0; z < 8; ++z) t += red[a][z][x];
        ws[P_IDX(s, n, r, a, x)] = t;
    }
}

// ---------------- K2: weights (wave 0) + streaming apply ----------------
__global__ __launch_bounds__(256)
void fa_apply(const float* __restrict__ mem, const float* __restrict__ ws,
              float* __restrict__ out)
{
    // XCD-chunk swizzle (2048 = 8 x 256): XCD k gets one full c-chunk.
    const int b = blockIdx.x;
    const int l = ((b & 7) << 8) | (b >> 3);
    const int r = l & 63;
    const int n = (l >> 6) & 3;
    const int c = l >> 8;       // 0..7 : 32-channel chunk

    const int x = threadIdx.x;  // lane
    const int g = threadIdx.y;  // 0..3

    __shared__ float wsh[5][WW];

    if (g == 0) {
        float tot[NACC];
        #pragma unroll
        for (int a = 0; a < NACC; ++a) {
            float t = 0.f;
            #pragma unroll
            for (int s = 0; s < SPLITS; ++s) t += ws[P_IDX(s, n, r, a, x)];
            tot[a] = t;
        }
        // neighbor-row pn^2 (split-summed); own row = tot[14]
        const int ra = max(r - 1, 0), rc = min(r + 1, HH - 1), rd = min(r + 2, HH - 1);
        float pnA = 0.f, pnC = 0.f, pnD = 0.f;
        #pragma unroll
        for (int s = 0; s < SPLITS; ++s) {
            pnA += ws[P_IDX(s, n, ra, 14, x)];
            pnC += ws[P_IDX(s, n, rc, 14, x)];
            pnD += ws[P_IDX(s, n, rd, 14, x)];
        }
        const float pnB = tot[14];

        const int xp1 = min(x + 1, WW - 1);
        const int xm1 = max(x - 1, 0);
        const int xp2 = min(x + 2, WW - 1);

        // realign M-space dots (+ boundary fixes)
        float dot[12];
        float t, t2, t63;
        t = __shfl(tot[1], xm1);  dot[0] = (x > 0)  ? t : tot[0];          // (-1,-1)
        dot[1] = tot[0];                                                    // (-1, 0)
        t = __shfl(tot[2], xp1);  dot[2] = (x < 63) ? t : tot[0];          // (-1,+1)
        t = __shfl(tot[5], xm1);  dot[3] = (x > 0)  ? t : tot[4];          // ( 0,-1)
        dot[4] = tot[4];                                                    // ( 0, 0)
        t = __shfl(tot[6], xp1);  dot[5] = (x < 63) ? t : tot[4];          // ( 0,+1)
        t = __shfl(tot[8], xm1);  dot[6] = (x > 0)  ? t : tot[7];          // (+1,-1)
        dot[7] = tot[7];                                                    // (+1, 0)
        t = __shfl(tot[9], xp1);  dot[8] = (x < 63) ? t : tot[7];          // (+1,+1)
        t2  = __shfl(tot[3],  xp2);
        t63 = __shfl(tot[2],  63);
        dot[9]  = (x < 62) ? t2 : ((x == 62) ? t63 : tot[0]);              // (-1,+2)
        t = __shfl(tot[11], xm1); dot[10] = (x > 0) ? t : tot[10];         // (+2,-1)
        t2  = __shfl(tot[13], xp2);
        t63 = __shfl(tot[12], 63);
        dot[11] = (x < 62) ? t2 : ((x == 62) ? t63 : tot[10]);             // (+2,+2)

        // pn^2 at offsets (positional -> clamped shfl is exact)
        float pn2o[12];
        pn2o[0]  = __shfl(pnA, xm1); pn2o[1]  = pnA; pn2o[2]  = __shfl(pnA, xp1);
        pn2o[3]  = __shfl(pnB, xm1); pn2o[4]  = pnB; pn2o[5]  = __shfl(pnB, xp1);
        pn2o[6]  = __shfl(pnC, xm1); pn2o[7]  = pnC; pn2o[8]  = __shfl(pnC, xp1);
        pn2o[9]  = __shfl(pnA, xp2);
        pn2o[10] = __shfl(pnD, xm1);
        pn2o[11] = __shfl(pnD, xp2);

        const float cn = sqrtf(tot[15]) + 1e-8f;
        const int ody[12] = {-1,-1,-1, 0,0,0, 1,1,1, -1, 2, 2};
        const int odx[12] = {-1, 0, 1,-1,0,1,-1,0,1,  2,-1, 2};

        float aff[12];
        #pragma unroll
        for (int o = 0; o < 12; ++o) {
            const float pn = sqrtf(pn2o[o]) + 1e-8f;
            aff[o] = fmaxf(dot[o] / (cn * pn), 0.f);
        }
        float mass = 0.f;
        #pragma unroll
        for (int o = 0; o < 9; ++o) {
            const bool valid = (r + ody[o] >= 0) && (r + ody[o] < HH) &&
                               (x + odx[o] >= 0) && (x + odx[o] < WW);
            if (valid) mass += aff[o];
        }
        const bool  cond      = (mass > -10.f) && (mass < 10.f);
        const float mass_safe = (mass > 0.f) ? mass : 1.f;

        const int aggo[4] = {0, 9, 10, 11};
        #pragma unroll
        for (int j = 0; j < 4; ++j) {
            const int  o     = aggo[j];
            const bool valid = (r + ody[o] >= 0) && (r + ody[o] < HH) &&
                               (x + odx[o] >= 0) && (x + odx[o] < WW);
            const float a = aff[o];
            wsh[j][x] = (valid && a > 0.f) ? (a / mass_safe) : 0.f;
        }
        wsh[4][x] = cond ? 1.f : 0.f;
    }
    __syncthreads();

    const float w0 = wsh[0][x], w1 = wsh[1][x], w2 = wsh[2][x], w3 = wsh[3][x];
    const float cf = wsh[4][x];

    const size_t noff = (size_t)n * DD * HWD;
    const float* __restrict__ mem_n = mem + noff;
    float* __restrict__ out_n       = out + noff;

    const int ym = max(r - 1, 0), yp = min(r + 2, HH - 1);
    const int xm = max(x - 1, 0), xp = min(x + 2, WW - 1);
    const int p0 = ym * WW + xm;   // (-1,-1)
    const int p1 = ym * WW + xp;   // (-1,+2)
    const int p2 = yp * WW + xm;   // (+2,-1)
    const int p3 = yp * WW + xp;   // (+2,+2)
    const int q  = r * WW + x;

    const int d0 = c * 32 + g * 8;
    #pragma unroll
    for (int k = 0; k < 8; ++k) {
        const int d = d0 + k;
        const float* __restrict__ md = mem_n + (size_t)d * HWD;
        const float m   = md[q];
        const float agg = w0 * md[p0] + w1 * md[p1] + w2 * md[p2] + w3 * md[p3];
        const float res = m + ((d > 0) ? agg : 0.f);
        out_n[(size_t)d * HWD + q] = (cf != 0.f) ? res : 0.f;
    }
}

extern "C" void kernel_launch(void* const* d_in, const int* in_sizes, int n_in,
                              void* d_out, int out_size, void* d_ws, size_t ws_size,
                              hipStream_t stream)
{
    const float* cur  = (const float*)d_in[0];
    const float* prev = (const float*)d_in[1];
    const float* mem  = (const float*)d_in[2];
    float* out        = (float*)d_out;
    float* ws         = (float*)d_ws;

    {   // K1: 1024 blocks (XCD-swizzled), 512 thr
        dim3 block(64, 8, 1), grid(1024, 1, 1);
        hipLaunchKernelGGL(fa_dots, grid, block, 0, stream, cur, prev, ws);
    }
    {   // K2: 2048 blocks (XCD-swizzled), 256 thr, weights + streaming
        dim3 block(64, 4, 1), grid(2048, 1, 1);
        hipLaunchKernelGGL(fa_apply, grid, block, 0, stream, mem, ws, out);
    }
}

// Round 8
// 101.773 us; speedup vs baseline: 3.5077x; 1.1083x over previous
//
#include <hip/hip_runtime.h>

// FeatureAlign, MI355X. N=4, D=256, H=W=64, fp32. Three kernels:
//  K1 fa_dots   : 12-offset dot partials in "M-space" — shift CUR by 3
//                 shfls/channel (not PREV by 9), + pn2/cn2. 1024 blocks.
//  K2 fa_weights: split-reduce partials in LDS, realign M-space dots by
//                 clamped LDS indexing (no shfl), weight math. 256 blocks.
//  K3 fa_apply  : stream mem + 4 weighted gathers -> out. 2048 blocks.
// History: coop grid.sync = 476us (r6, reverted); K2-fused-into-K3 = +8us
// from 8x redundant weight recompute (r7, reverted).

#define HH 64
#define WW 64
#define DD 256
#define HWD (HH * WW)
#define SPLITS 4
#define CPB (DD / SPLITS)   // 64 channels per split-unit
#define CPT (CPB / 8)       // 8 channels per thread

// acc layout (M-space), X in {A=row r-1, B=row r, C=row r+1, D=row r+2}:
//  0 dA0  1 dAm  2 dAp  3 dA2
//  4 dB0  5 dBm  6 dBp
//  7 dC0  8 dCm  9 dCp
// 10 dD0 11 dDm 12 dDp 13 dD2
// 14 pn2(own) 15 cn2(own)
// dX0[x]=sum c[x]X[x]; dXm[x]=sum c[min(x+1,63)]X[x];
// dXp[x]=sum c[max(x-1,0)]X[x]; dX2[x]=sum c[max(x-2,0)]X[x].
// Realign: dot(X,-1)[x] = x>0 ? dXm[x-1] : dX0[0]
//          dot(X,+1)[x] = x<63 ? dXp[x+1] : dX0[63]
//          dot(X,+2)[x] = x<62 ? dX2[x+2] : (x==62 ? dXp[63] : dX0[63])
#define NACC 16

// d_ws: P[s][n][r][a][x] : 4*4*64*16*64 = 1,048,576 floats (4 MB)
//       W[n][j][r][x]    : 4*5*64*64    =    81,920 floats
#define P_IDX(s, n, r, a, x) (((((size_t)(s) * 4 + (n)) * HH + (r)) * NACC + (a)) * WW + (x))
#define W_OFF ((size_t)SPLITS * 4 * HH * NACC * WW)
#define W_IDX(n, j, r, x) (W_OFF + ((((size_t)(n) * 5 + (j)) * HH + (r)) * WW + (x)))

// ---------------- K1: M-space dot partials ----------------
__global__ __launch_bounds__(512)
void fa_dots(const float* __restrict__ cur, const float* __restrict__ prev,
             float* __restrict__ ws)
{
    // XCD-chunk swizzle (1024 = 8 x 128): XCD k gets contiguous r.
    const int b = blockIdx.x;
    const int l = ((b & 7) << 7) | (b >> 3);
    const int r = l & 63;
    const int n = (l >> 6) & 3;
    const int s = l >> 8;

    const int x  = threadIdx.x;   // lane
    const int tz = threadIdx.y;   // 0..7

    const size_t noff = (size_t)n * DD * HWD;
    const float* __restrict__ cur_n  = cur  + noff;
    const float* __restrict__ prev_n = prev + noff;

    const int xp1 = min(x + 1, WW - 1);
    const int xm1 = max(x - 1, 0);
    const int xm2 = max(x - 2, 0);

    const int rA = max(r - 1, 0)      * WW + x;
    const int rB = r                  * WW + x;
    const int rC = min(r + 1, HH - 1) * WW + x;
    const int rD = min(r + 2, HH - 1) * WW + x;

    float acc[NACC];
    #pragma unroll
    for (int a = 0; a < NACC; ++a) acc[a] = 0.f;

    const int d0 = s * CPB + tz * CPT;
    const float* __restrict__ cd = cur_n  + (size_t)d0 * HWD;
    const float* __restrict__ pd = prev_n + (size_t)d0 * HWD;

    float c_ = cd[rB];
    float vA = pd[rA];
    float vB = pd[rB];
    float vC = pd[rC];
    float vD = pd[rD];

    #pragma unroll
    for (int k = 0; k < CPT; ++k) {
        float cN = 0.f, aN = 0.f, bN = 0.f, ccN = 0.f, dN = 0.f;
        if (k + 1 < CPT) {
            const float* __restrict__ cd2 = cd + (size_t)(k + 1) * HWD;
            const float* __restrict__ pd2 = pd + (size_t)(k + 1) * HWD;
            cN  = cd2[rB];
            aN  = pd2[rA];
            bN  = pd2[rB];
            ccN = pd2[rC];
            dN  = pd2[rD];
        }

        // shift CUR: 3 shfls total (vs 9 shifting PREV)
        const float cp1 = __shfl(c_, xp1);   // c[x+1] (clamped)
        const float cm1 = __shfl(c_, xm1);   // c[x-1]
        const float cm2 = __shfl(c_, xm2);   // c[x-2]

        acc[0]  = fmaf(c_,  vA, acc[0]);
        acc[1]  = fmaf(cp1, vA, acc[1]);
        acc[2]  = fmaf(cm1, vA, acc[2]);
        acc[3]  = fmaf(cm2, vA, acc[3]);
        acc[4]  = fmaf(c_,  vB, acc[4]);
        acc[5]  = fmaf(cp1, vB, acc[5]);
        acc[6]  = fmaf(cm1, vB, acc[6]);
        acc[7]  = fmaf(c_,  vC, acc[7]);
        acc[8]  = fmaf(cp1, vC, acc[8]);
        acc[9]  = fmaf(cm1, vC, acc[9]);
        acc[10] = fmaf(c_,  vD, acc[10]);
        acc[11] = fmaf(cp1, vD, acc[11]);
        acc[12] = fmaf(cm1, vD, acc[12]);
        acc[13] = fmaf(cm2, vD, acc[13]);
        acc[14] = fmaf(vB,  vB, acc[14]);   // pn^2 own
        acc[15] = fmaf(c_,  c_, acc[15]);   // cn^2 own

        c_ = cN; vA = aN; vB = bN; vC = ccN; vD = dN;
    }

    __shared__ float red[NACC][8][WW];   // 32 KB
    #pragma unroll
    for (int a = 0; a < NACC; ++a) red[a][tz][x] = acc[a];
    __syncthreads();
    for (int a = tz; a < NACC; a += 8) {
        float t = 0.f;
        #pragma unroll
        for (int z = 0; z < 8; ++z) t += red[a][z][x];
        ws[P_IDX(s, n, r, a, x)] = t;
    }
}

// ---------------- K2: split-reduce + realign + weights ----------------
__global__ __launch_bounds__(256)
void fa_weights(float* __restrict__ ws)
{
    const int x = threadIdx.x;   // 0..63
    const int g = threadIdx.y;   // 0..3
    const int r = blockIdx.x;
    const int n = blockIdx.y;

    __shared__ float tot[NACC][WW];
    __shared__ float png[4][WW];     // pn^2 rows A,B,C,D (split-summed)

    for (int a = g; a < NACC; a += 4) {
        float t = 0.f;
        #pragma unroll
        for (int s = 0; s < SPLITS; ++s) t += ws[P_IDX(s, n, r, a, x)];
        tot[a][x] = t;
    }
    {   // wave g handles pn^2 row g
        const int rows[4] = { max(r - 1, 0), r, min(r + 1, HH - 1), min(r + 2, HH - 1) };
        float t = 0.f;
        #pragma unroll
        for (int s = 0; s < SPLITS; ++s) t += ws[P_IDX(s, n, rows[g], 14, x)];
        png[g][x] = t;
    }
    __syncthreads();

    if (g == 0) {
        const int xm = max(x - 1, 0);
        const int xp = min(x + 1, WW - 1);
        const int x2 = min(x + 2, WW - 1);

        // realign M-space dots via clamped LDS indexing + boundary selects
        float dot[12];
        dot[0]  = (x > 0)  ? tot[1][xm]  : tot[0][0];                       // (-1,-1)
        dot[1]  = tot[0][x];                                                // (-1, 0)
        dot[2]  = (x < 63) ? tot[2][xp]  : tot[0][63];                      // (-1,+1)
        dot[3]  = (x > 0)  ? tot[5][xm]  : tot[4][0];                       // ( 0,-1)
        dot[4]  = tot[4][x];                                                // ( 0, 0)
        dot[5]  = (x < 63) ? tot[6][xp]  : tot[4][63];                      // ( 0,+1)
        dot[6]  = (x > 0)  ? tot[8][xm]  : tot[7][0];                       // (+1,-1)
        dot[7]  = tot[7][x];                                                // (+1, 0)
        dot[8]  = (x < 63) ? tot[9][xp]  : tot[7][63];                      // (+1,+1)
        dot[9]  = (x < 62) ? tot[3][x2]  : ((x == 62) ? tot[2][63] : tot[0][63]);   // (-1,+2)
        dot[10] = (x > 0)  ? tot[11][xm] : tot[10][0];                      // (+2,-1)
        dot[11] = (x < 62) ? tot[13][x2] : ((x == 62) ? tot[12][63] : tot[10][63]); // (+2,+2)

        // pn^2 at the 12 offsets: positional, clamped index is exact
        float pn2o[12];
        pn2o[0]  = png[0][xm]; pn2o[1]  = png[0][x]; pn2o[2]  = png[0][xp];
        pn2o[3]  = png[1][xm]; pn2o[4]  = png[1][x]; pn2o[5]  = png[1][xp];
        pn2o[6]  = png[2][xm]; pn2o[7]  = png[2][x]; pn2o[8]  = png[2][xp];
        pn2o[9]  = png[0][x2];
        pn2o[10] = png[3][xm];
        pn2o[11] = png[3][x2];

        const float cn = sqrtf(tot[15][x]) + 1e-8f;
        const int ody[12] = {-1,-1,-1, 0,0,0, 1,1,1, -1, 2, 2};
        const int odx[12] = {-1, 0, 1,-1,0,1,-1,0,1,  2,-1, 2};

        float aff[12];
        #pragma unroll
        for (int o = 0; o < 12; ++o) {
            const float pn = sqrtf(pn2o[o]) + 1e-8f;
            aff[o] = fmaxf(dot[o] / (cn * pn), 0.f);
        }
        float mass = 0.f;
        #pragma unroll
        for (int o = 0; o < 9; ++o) {
            const bool valid = (r + ody[o] >= 0) && (r + ody[o] < HH) &&
                               (x + odx[o] >= 0) && (x + odx[o] < WW);
            if (valid) mass += aff[o];
        }
        const bool  cond      = (mass > -10.f) && (mass < 10.f);
        const float mass_safe = (mass > 0.f) ? mass : 1.f;

        const int aggo[4] = {0, 9, 10, 11};
        #pragma unroll
        for (int j = 0; j < 4; ++j) {
            const int  o     = aggo[j];
            const bool valid = (r + ody[o] >= 0) && (r + ody[o] < HH) &&
                               (x + odx[o] >= 0) && (x + odx[o] < WW);
            const float a = aff[o];
            ws[W_IDX(n, j, r, x)] = (valid && a > 0.f) ? (a / mass_safe) : 0.f;
        }
        ws[W_IDX(n, 4, r, x)] = cond ? 1.f : 0.f;
    }
}

// ---------------- K3: streaming apply ----------------
__global__ __launch_bounds__(256)
void fa_apply(const float* __restrict__ mem, const float* __restrict__ ws,
              float* __restrict__ out)
{
    // XCD-chunk swizzle (2048 = 8 x 256)
    const int b = blockIdx.x;
    const int l = ((b & 7) << 8) | (b >> 3);
    const int r = l & 63;
    const int t = l >> 6;
    const int n = t & 3;
    const int c = t >> 2;       // 0..7 : 32-channel chunk

    const int x = threadIdx.x;
    const int g = threadIdx.y;  // 0..3

    const size_t noff = (size_t)n * DD * HWD;
    const float* __restrict__ mem_n = mem + noff;
    float* __restrict__ out_n       = out + noff;

    const float w0 = ws[W_IDX(n, 0, r, x)];
    const float w1 = ws[W_IDX(n, 1, r, x)];
    const float w2 = ws[W_IDX(n, 2, r, x)];
    const float w3 = ws[W_IDX(n, 3, r, x)];
    const float cf = ws[W_IDX(n, 4, r, x)];

    const int ym = max(r - 1, 0), yp = min(r + 2, HH - 1);
    const int xm = max(x - 1, 0), xp = min(x + 2, WW - 1);
    const int p0 = ym * WW + xm;   // (-1,-1)
    const int p1 = ym * WW + xp;   // (-1,+2)
    const int p2 = yp * WW + xm;   // (+2,-1)
    const int p3 = yp * WW + xp;   // (+2,+2)
    const int q  = r * WW + x;

    const int d0 = c * 32 + g * 8;
    #pragma unroll
    for (int k = 0; k < 8; ++k) {
        const int d = d0 + k;
        const float* __restrict__ md = mem_n + (size_t)d * HWD;
        const float m   = md[q];
        const float agg = w0 * md[p0] + w1 * md[p1] + w2 * md[p2] + w3 * md[p3];
        const float res = m + ((d > 0) ? agg : 0.f);
        out_n[(size_t)d * HWD + q] = (cf != 0.f) ? res : 0.f;
    }
}

extern "C" void kernel_launch(void* const* d_in, const int* in_sizes, int n_in,
                              void* d_out, int out_size, void* d_ws, size_t ws_size,
                              hipStream_t stream)
{
    const float* cur  = (const float*)d_in[0];
    const float* prev = (const float*)d_in[1];
    const float* mem  = (const float*)d_in[2];
    float* out        = (float*)d_out;
    float* ws         = (float*)d_ws;

    {   // K1: 1024 blocks (XCD-swizzled), 512 thr
        dim3 block(64, 8, 1), grid(1024, 1, 1);
        hipLaunchKernelGGL(fa_dots, grid, block, 0, stream, cur, prev, ws);
    }
    {   // K2: 256 blocks, 256 thr
        dim3 block(64, 4, 1), grid(HH, 4, 1);
        hipLaunchKernelGGL(fa_weights, grid, block, 0, stream, ws);
    }
    {   // K3: 2048 blocks (XCD-swizzled), 256 thr, streaming
        dim3 block(64, 4, 1), grid(2048, 1, 1);
        hipLaunchKernelGGL(fa_apply, grid, block, 0, stream, mem, ws, out);
    }
}